// Round 1
// baseline (654.300 us; speedup 1.0000x reference)
//
#include <hip/hip_runtime.h>

#define BB 2
#define NN 6272
#define CC 256
#define CI 128

typedef __bf16 bf16;
typedef __attribute__((ext_vector_type(8))) __bf16 bf16x8;
typedef __attribute__((ext_vector_type(4))) float f32x4;

// ---------------- kernel 1: g/theta/phi projections (fp32 vector) ----------------
__global__ __launch_bounds__(128) void proj_kernel(
    const float* __restrict__ x,
    const float* __restrict__ Wg, const float* __restrict__ bg,
    const float* __restrict__ Wt, const float* __restrict__ bt,
    const float* __restrict__ Wp, const float* __restrict__ bp,
    bf16* __restrict__ th, bf16* __restrict__ ph, bf16* __restrict__ gg)
{
    __shared__ float xs[16][257];   // 16 positions x 256 ch, pad to break store conflicts
    const int p0  = blockIdx.x * 16;      // fused (b*N + n) position base
    const int tid = threadIdx.x;          // 0..127

    // stage x tile: thread -> row tid>>3, 32 consecutive channels
    {
        const int pr = tid >> 3, c0 = (tid & 7) * 32;
        const float* xsrc = x + (size_t)(p0 + pr) * CC + c0;
        #pragma unroll
        for (int i = 0; i < 8; ++i) {
            float4 v = *reinterpret_cast<const float4*>(xsrc + 4 * i);
            xs[pr][c0 + 4*i + 0] = v.x;
            xs[pr][c0 + 4*i + 1] = v.y;
            xs[pr][c0 + 4*i + 2] = v.z;
            xs[pr][c0 + 4*i + 3] = v.w;
        }
    }
    __syncthreads();

    const int ci = tid;                   // output channel 0..127
    float ag[16], at[16], ap[16];
    #pragma unroll
    for (int p = 0; p < 16; ++p) { ag[p]=0.f; at[p]=0.f; ap[p]=0.f; }

    for (int c = 0; c < CC; ++c) {
        float wg = Wg[c*CI + ci];
        float wt = Wt[c*CI + ci];
        float wp = Wp[c*CI + ci];
        #pragma unroll
        for (int p = 0; p < 16; ++p) {
            float xv = xs[p][c];          // broadcast read
            ag[p] = fmaf(xv, wg, ag[p]);
            at[p] = fmaf(xv, wt, at[p]);
            ap[p] = fmaf(xv, wp, ap[p]);
        }
    }
    const float bgv = bg[ci], btv = bt[ci], bpv = bp[ci];
    #pragma unroll
    for (int p = 0; p < 16; ++p) {
        size_t idx = (size_t)(p0 + p) * CI + ci;
        gg[idx] = (bf16)(ag[p] + bgv);
        th[idx] = (bf16)(at[p] + btv);
        ph[idx] = (bf16)(ap[p] + bpv);
    }
}

// ---------------- kernel 2: flash attention (unscaled softmax) ----------------
// block = 256 thr (4 waves); wave owns 16 q-rows; KV tile = 32.
// S = theta @ phi^T via mfma_f32_16x16x32_bf16:
//   A frag: row = lane&15, k = (lane>>4)*8 + j   (contiguous bf16x8)
//   B frag: col = lane&15, k = (lane>>4)*8 + j
//   D:      col = lane&15, row = (lane>>4)*4 + reg
__global__ __launch_bounds__(256) void attn_kernel(
    const bf16* __restrict__ th, const bf16* __restrict__ ph,
    const bf16* __restrict__ gg, float* __restrict__ y)
{
    __shared__ __align__(16) bf16 g_lds[CI][40];      // g tile transposed [ci][kv], pad 40
    __shared__ __align__(16) bf16 p_lds[4][16][40];   // per-wave P tile [q][kv], pad 40

    const int b    = blockIdx.y;
    const int q0   = blockIdx.x * 64;
    const int tid  = threadIdx.x;
    const int wid  = tid >> 6;
    const int lane = tid & 63;
    const int l15  = lane & 15;
    const int lg   = lane >> 4;      // 0..3
    const int qw   = q0 + wid * 16;

    const bf16* thb = th + (size_t)b * NN * CI;
    const bf16* phb = ph + (size_t)b * NN * CI;
    const bf16* ggb = gg + (size_t)b * NN * CI;

    // theta A-fragments for this wave's 16 q-rows (K=128 -> 4 frags), loaded once
    bf16x8 afr[4];
    {
        const bf16* trow = thb + (size_t)(qw + l15) * CI + lg * 8;
        #pragma unroll
        for (int kk = 0; kk < 4; ++kk)
            afr[kk] = *reinterpret_cast<const bf16x8*>(trow + kk * 32);
    }

    f32x4 acc[8];                                  // Y: 8 ci-tiles of 16
    #pragma unroll
    for (int t = 0; t < 8; ++t) acc[t] = (f32x4){0.f, 0.f, 0.f, 0.f};
    float m[4], lsum[4];
    #pragma unroll
    for (int r = 0; r < 4; ++r) { m[r] = -1e30f; lsum[r] = 0.f; }

    const int kvr = tid >> 3, c0s = (tid & 7) * 16;  // g staging assignment

    for (int kv0 = 0; kv0 < NN; kv0 += 32) {
        __syncthreads();   // previous iter's g_lds reads done before overwrite
        {   // stage g tile transposed: g_lds[ci][kv]
            const bf16* gsrc = ggb + (size_t)(kv0 + kvr) * CI + c0s;
            bf16x8 v0 = *reinterpret_cast<const bf16x8*>(gsrc);
            bf16x8 v1 = *reinterpret_cast<const bf16x8*>(gsrc + 8);
            #pragma unroll
            for (int i = 0; i < 8; ++i) {
                g_lds[c0s + i][kvr]     = v0[i];
                g_lds[c0s + 8 + i][kvr] = v1[i];
            }
        }
        __syncthreads();

        // S tiles: 16 q-rows x 32 kv-cols (two 16x16 D tiles)
        f32x4 s0 = {0.f,0.f,0.f,0.f}, s1 = {0.f,0.f,0.f,0.f};
        {
            const bf16* prow0 = phb + (size_t)(kv0 + l15) * CI + lg * 8;
            const bf16* prow1 = prow0 + (size_t)16 * CI;
            #pragma unroll
            for (int kk = 0; kk < 4; ++kk) {
                bf16x8 b0 = *reinterpret_cast<const bf16x8*>(prow0 + kk * 32);
                bf16x8 b1 = *reinterpret_cast<const bf16x8*>(prow1 + kk * 32);
                s0 = __builtin_amdgcn_mfma_f32_16x16x32_bf16(afr[kk], b0, s0, 0, 0, 0);
                s1 = __builtin_amdgcn_mfma_f32_16x16x32_bf16(afr[kk], b1, s1, 0, 0, 0);
            }
        }

        // online softmax over the 32 new cols; row r lives on lanes {lg group}, reg r
        float scale_[4];
        #pragma unroll
        for (int r = 0; r < 4; ++r) {
            float tm = fmaxf(s0[r], s1[r]);
            tm = fmaxf(tm, __shfl_xor(tm, 1));
            tm = fmaxf(tm, __shfl_xor(tm, 2));
            tm = fmaxf(tm, __shfl_xor(tm, 4));
            tm = fmaxf(tm, __shfl_xor(tm, 8));
            float mn = fmaxf(m[r], tm);
            float sc = __expf(m[r] - mn);
            m[r] = mn;
            float p0v = __expf(s0[r] - mn);
            float p1v = __expf(s1[r] - mn);
            s0[r] = p0v; s1[r] = p1v;
            float rs = p0v + p1v;
            rs += __shfl_xor(rs, 1);
            rs += __shfl_xor(rs, 2);
            rs += __shfl_xor(rs, 4);
            rs += __shfl_xor(rs, 8);
            lsum[r] = lsum[r] * sc + rs;
            scale_[r] = sc;
        }
        #pragma unroll
        for (int t = 0; t < 8; ++t) {
            #pragma unroll
            for (int r = 0; r < 4; ++r) acc[t][r] *= scale_[r];
        }

        // P (D-layout) -> LDS -> A-frag layout
        #pragma unroll
        for (int r = 0; r < 4; ++r) {
            const int row = lg * 4 + r;
            p_lds[wid][row][l15]      = (bf16)s0[r];
            p_lds[wid][row][16 + l15] = (bf16)s1[r];
        }
        bf16x8 pa = *reinterpret_cast<const bf16x8*>(&p_lds[wid][l15][lg * 8]);

        // Y += P @ g   (B frag from transposed g_lds: contiguous kv at fixed ci)
        #pragma unroll
        for (int t = 0; t < 8; ++t) {
            bf16x8 gb = *reinterpret_cast<const bf16x8*>(&g_lds[t * 16 + l15][lg * 8]);
            acc[t] = __builtin_amdgcn_mfma_f32_16x16x32_bf16(pa, gb, acc[t], 0, 0, 0);
        }
    }

    float inv[4];
    #pragma unroll
    for (int r = 0; r < 4; ++r) inv[r] = 1.0f / lsum[r];
    #pragma unroll
    for (int t = 0; t < 8; ++t) {
        #pragma unroll
        for (int r = 0; r < 4; ++r) {
            size_t idx = ((size_t)b * NN + qw + lg * 4 + r) * CI + t * 16 + l15;
            y[idx] = acc[t][r] * inv[r];
        }
    }
}

// ---------------- kernel 3: y@Wo + BN(inference) + residual ----------------
__global__ __launch_bounds__(256) void out_kernel(
    const float* __restrict__ x, const float* __restrict__ y,
    const float* __restrict__ Wo, const float* __restrict__ bo,
    const float* __restrict__ gamma, const float* __restrict__ beta,
    const float* __restrict__ mmean, const float* __restrict__ mvar,
    float* __restrict__ out)
{
    __shared__ float ys[16][132];
    const int p0  = blockIdx.x * 16;
    const int tid = threadIdx.x;   // 0..255 -> output channel
    {
        const int pr = tid >> 4, cc0 = (tid & 15) * 8;
        const float* ysrc = y + (size_t)(p0 + pr) * CI + cc0;
        float4 a0 = *reinterpret_cast<const float4*>(ysrc);
        float4 a1 = *reinterpret_cast<const float4*>(ysrc + 4);
        *reinterpret_cast<float4*>(&ys[pr][cc0])     = a0;
        *reinterpret_cast<float4*>(&ys[pr][cc0 + 4]) = a1;
    }
    __syncthreads();

    const int c = tid;
    float a[16];
    #pragma unroll
    for (int p = 0; p < 16; ++p) a[p] = 0.f;
    for (int k = 0; k < CI; ++k) {
        float w = Wo[k * CC + c];
        #pragma unroll
        for (int p = 0; p < 16; ++p)
            a[p] = fmaf(ys[p][k], w, a[p]);
    }
    const float sc = gamma[c] * rsqrtf(mvar[c] + 1e-3f);
    const float sh = beta[c] + sc * (bo[c] - mmean[c]);
    #pragma unroll
    for (int p = 0; p < 16; ++p) {
        size_t idx = (size_t)(p0 + p) * CC + c;
        out[idx] = x[idx] + sc * a[p] + sh;
    }
}

extern "C" void kernel_launch(void* const* d_in, const int* in_sizes, int n_in,
                              void* d_out, int out_size, void* d_ws, size_t ws_size,
                              hipStream_t stream)
{
    const float* x     = (const float*)d_in[0];
    const float* Wg    = (const float*)d_in[1];
    const float* bg    = (const float*)d_in[2];
    const float* Wt    = (const float*)d_in[3];
    const float* bt    = (const float*)d_in[4];
    const float* Wp    = (const float*)d_in[5];
    const float* bp    = (const float*)d_in[6];
    const float* Wo    = (const float*)d_in[7];
    const float* bo    = (const float*)d_in[8];
    const float* gamma = (const float*)d_in[9];
    const float* beta  = (const float*)d_in[10];
    const float* mmean = (const float*)d_in[11];
    const float* mvar  = (const float*)d_in[12];
    float* out = (float*)d_out;

    const size_t PB = (size_t)BB * NN * CI;          // 1,605,632 elems per projection
    bf16* th = (bf16*)d_ws;
    bf16* ph = th + PB;
    bf16* gg = ph + PB;
    float* yv = (float*)((char*)d_ws + 3 * PB * sizeof(bf16));
    // total ws use: 3*PB*2 + PB*4 = ~16.1 MB

    proj_kernel<<<dim3(BB * NN / 16), 128, 0, stream>>>(x, Wg, bg, Wt, bt, Wp, bp, th, ph, gg);
    attn_kernel<<<dim3(NN / 64, BB), 256, 0, stream>>>(th, ph, gg, yv);
    out_kernel<<<dim3(BB * NN / 16), 256, 0, stream>>>(x, yv, Wo, bo, gamma, beta, mmean, mvar, out);
}

// Round 2
// 318.775 us; speedup vs baseline: 2.0525x; 2.0525x over previous
//
#include <hip/hip_runtime.h>

#define BB 2
#define NN 6272
#define CC 256
#define CI 128
#define SEG 7
#define KVSEG (NN / SEG)          // 896 kv per segment
#define LOG2E 1.44269504088896f

typedef _Float16 f16;
typedef __attribute__((ext_vector_type(8))) _Float16 f16x8;
typedef __attribute__((ext_vector_type(4))) float f32x4;

// ---------------- kernel 1: g/theta/phi projections (fp32 vector, fp16 out) ----------
// th = (x@Wt + bt) * LOG2E   [b][n][ci]   (pre-scaled so softmax uses exp2)
// ph = (x@Wp + bp)           [b][n][ci]
// gT = (x@Wg + bg)           [b][ci][n]   (transposed for PV B-fragments)
__global__ __launch_bounds__(128) void proj_kernel(
    const float* __restrict__ x,
    const float* __restrict__ Wg, const float* __restrict__ bg,
    const float* __restrict__ Wt, const float* __restrict__ bt,
    const float* __restrict__ Wp, const float* __restrict__ bp,
    f16* __restrict__ th, f16* __restrict__ ph, f16* __restrict__ gT)
{
    __shared__ float xs[16][257];
    const int p0  = blockIdx.x * 16;          // fused (b*NN + n) base; blocks never straddle b
    const int tid = threadIdx.x;

    {
        const int pr = tid >> 3, c0 = (tid & 7) * 32;
        const float* xsrc = x + (size_t)(p0 + pr) * CC + c0;
        #pragma unroll
        for (int i = 0; i < 8; ++i) {
            float4 v = *reinterpret_cast<const float4*>(xsrc + 4 * i);
            xs[pr][c0 + 4*i + 0] = v.x;
            xs[pr][c0 + 4*i + 1] = v.y;
            xs[pr][c0 + 4*i + 2] = v.z;
            xs[pr][c0 + 4*i + 3] = v.w;
        }
    }
    __syncthreads();

    const int ci = tid;
    float ag[16], at[16], ap[16];
    #pragma unroll
    for (int p = 0; p < 16; ++p) { ag[p]=0.f; at[p]=0.f; ap[p]=0.f; }

    for (int c = 0; c < CC; ++c) {
        float wg = Wg[c*CI + ci];
        float wt = Wt[c*CI + ci];
        float wp = Wp[c*CI + ci];
        #pragma unroll
        for (int p = 0; p < 16; ++p) {
            float xv = xs[p][c];
            ag[p] = fmaf(xv, wg, ag[p]);
            at[p] = fmaf(xv, wt, at[p]);
            ap[p] = fmaf(xv, wp, ap[p]);
        }
    }
    const float bgv = bg[ci], btv = bt[ci], bpv = bp[ci];
    const int b  = (p0 >= NN) ? 1 : 0;
    const int n0 = p0 - b * NN;

    f16 gbuf[16];
    #pragma unroll
    for (int p = 0; p < 16; ++p) {
        size_t idx = (size_t)(p0 + p) * CI + ci;
        th[idx] = (f16)((at[p] + btv) * LOG2E);
        ph[idx] = (f16)(ap[p] + bpv);
        gbuf[p] = (f16)(ag[p] + bgv);
    }
    // transposed g: 16 contiguous halfs = two 16B stores (32B-aligned: n0 % 16 == 0)
    f16* gdst = gT + ((size_t)b * CI + ci) * NN + n0;
    *reinterpret_cast<float4*>(gdst)     = *reinterpret_cast<const float4*>(&gbuf[0]);
    *reinterpret_cast<float4*>(gdst + 8) = *reinterpret_cast<const float4*>(&gbuf[8]);
}

// ---------------- kernel 2: split-KV flash attention, no barriers --------------------
// grid (NN/128, SEG, BB); 4 waves/block; wave owns 32 q rows (2 MFMA row-tiles).
// KV tile = 32. Logits already in log2 domain (theta pre-scaled).
// Defer-max: P = exp2(s - m), m lags true max by <= 11 -> P <= 2048 fits fp16.
// Row sum l accumulated via all-ones B-fragment MFMA (no shuffle reduce).
__global__ __launch_bounds__(256, 3) void attn_kernel(
    const f16* __restrict__ th, const f16* __restrict__ ph,
    const f16* __restrict__ gT, float* __restrict__ pacc, float* __restrict__ pml)
{
    __shared__ __align__(16) f16 p_lds[4][2][16][40];   // [wave][qtile][row][kv(32)+pad]

    const int b    = blockIdx.z;
    const int seg  = blockIdx.y;
    const int q0   = blockIdx.x * 128;
    const int tid  = threadIdx.x;
    const int wid  = tid >> 6;
    const int lane = tid & 63;
    const int l15  = lane & 15;
    const int lg   = lane >> 4;
    const int qw   = q0 + wid * 32;

    const f16* thb = th + (size_t)b * NN * CI;
    const f16* phb = ph + (size_t)b * NN * CI;
    const f16* gTb = gT + (size_t)b * CI * NN;

    // theta A-fragments: 2 q-tiles x 4 k-frags, kept in registers for the whole segment
    f16x8 af[2][4];
    #pragma unroll
    for (int qt = 0; qt < 2; ++qt) {
        const f16* trow = thb + (size_t)(qw + qt*16 + l15) * CI + lg * 8;
        #pragma unroll
        for (int kk = 0; kk < 4; ++kk)
            af[qt][kk] = *reinterpret_cast<const f16x8*>(trow + kk * 32);
    }

    f32x4 acc[2][8];     // Y accum: 2 q-tiles x 8 ci-tiles
    f32x4 accl[2];       // row-sum accum (ones column)
    float m[2][4];
    #pragma unroll
    for (int qt = 0; qt < 2; ++qt) {
        #pragma unroll
        for (int ct = 0; ct < 8; ++ct) acc[qt][ct] = (f32x4){0.f,0.f,0.f,0.f};
        accl[qt] = (f32x4){0.f,0.f,0.f,0.f};
        #pragma unroll
        for (int r = 0; r < 4; ++r) m[qt][r] = -INFINITY;
    }

    const f16x8 onesf = {(f16)1,(f16)1,(f16)1,(f16)1,(f16)1,(f16)1,(f16)1,(f16)1};
    const int kv_base = seg * KVSEG;

    for (int it = 0; it < KVSEG / 32; ++it) {
        const int kv = kv_base + it * 32;

        // ---- QK^T: 16 q x 32 kv per q-tile (2 col-tiles x 4 k-frags) ----
        f32x4 s[2][2];
        #pragma unroll
        for (int qt = 0; qt < 2; ++qt)
            #pragma unroll
            for (int t = 0; t < 2; ++t) s[qt][t] = (f32x4){0.f,0.f,0.f,0.f};

        #pragma unroll
        for (int t = 0; t < 2; ++t) {
            const f16* pcol = phb + (size_t)(kv + t*16 + l15) * CI + lg * 8;
            #pragma unroll
            for (int kk = 0; kk < 4; ++kk) {
                f16x8 bf = *reinterpret_cast<const f16x8*>(pcol + kk * 32);
                s[0][t] = __builtin_amdgcn_mfma_f32_16x16x32_f16(af[0][kk], bf, s[0][t], 0, 0, 0);
                s[1][t] = __builtin_amdgcn_mfma_f32_16x16x32_f16(af[1][kk], bf, s[1][t], 0, 0, 0);
            }
        }

        // ---- online max (log2 domain), defer-rescale ----
        float tm[2][4];
        int need = 0;
        #pragma unroll
        for (int qt = 0; qt < 2; ++qt) {
            #pragma unroll
            for (int r = 0; r < 4; ++r) {
                float v = fmaxf(s[qt][0][r], s[qt][1][r]);
                v = fmaxf(v, __shfl_xor(v, 1));
                v = fmaxf(v, __shfl_xor(v, 2));
                v = fmaxf(v, __shfl_xor(v, 4));
                v = fmaxf(v, __shfl_xor(v, 8));
                tm[qt][r] = v;
                need |= (v > m[qt][r] + 11.0f) ? 1 : 0;
            }
        }
        if (__any(need)) {
            #pragma unroll
            for (int qt = 0; qt < 2; ++qt) {
                #pragma unroll
                for (int r = 0; r < 4; ++r) {
                    float nm = fmaxf(m[qt][r], tm[qt][r]);
                    float sc = __builtin_amdgcn_exp2f(m[qt][r] - nm);
                    m[qt][r] = nm;
                    #pragma unroll
                    for (int ct = 0; ct < 8; ++ct) acc[qt][ct][r] *= sc;
                    accl[qt][r] *= sc;
                }
            }
        }

        // ---- P = exp2(s - m), cvt fp16, round-trip through per-wave LDS ----
        #pragma unroll
        for (int qt = 0; qt < 2; ++qt)
            #pragma unroll
            for (int t = 0; t < 2; ++t)
                #pragma unroll
                for (int r = 0; r < 4; ++r) {
                    float pv = __builtin_amdgcn_exp2f(s[qt][t][r] - m[qt][r]);
                    p_lds[wid][qt][lg*4 + r][t*16 + l15] = (f16)pv;
                }

        f16x8 pa[2];
        #pragma unroll
        for (int qt = 0; qt < 2; ++qt)
            pa[qt] = *reinterpret_cast<const f16x8*>(&p_lds[wid][qt][l15][lg * 8]);

        // ---- Y += P @ g  (B-fragments straight from global gT) ----
        #pragma unroll
        for (int ct = 0; ct < 8; ++ct) {
            const f16* grow = gTb + (size_t)(ct*16 + l15) * NN + kv + lg * 8;
            f16x8 gb = *reinterpret_cast<const f16x8*>(grow);
            acc[0][ct] = __builtin_amdgcn_mfma_f32_16x16x32_f16(pa[0], gb, acc[0][ct], 0, 0, 0);
            acc[1][ct] = __builtin_amdgcn_mfma_f32_16x16x32_f16(pa[1], gb, acc[1][ct], 0, 0, 0);
        }
        accl[0] = __builtin_amdgcn_mfma_f32_16x16x32_f16(pa[0], onesf, accl[0], 0, 0, 0);
        accl[1] = __builtin_amdgcn_mfma_f32_16x16x32_f16(pa[1], onesf, accl[1], 0, 0, 0);
    }

    // ---- store partials ----
    float* pb = pacc + ((size_t)(b*SEG + seg) * NN + qw) * CI;
    #pragma unroll
    for (int qt = 0; qt < 2; ++qt)
        #pragma unroll
        for (int ct = 0; ct < 8; ++ct)
            #pragma unroll
            for (int r = 0; r < 4; ++r)
                pb[(size_t)(qt*16 + lg*4 + r) * CI + ct*16 + l15] = acc[qt][ct][r];

    if (l15 == 0) {
        float* mlb = pml + ((size_t)(b*SEG + seg) * NN + qw) * 2;
        #pragma unroll
        for (int qt = 0; qt < 2; ++qt)
            #pragma unroll
            for (int r = 0; r < 4; ++r) {
                int row = qt*16 + lg*4 + r;
                mlb[row*2 + 0] = m[qt][r];
                mlb[row*2 + 1] = accl[qt][r];
            }
    }
}

// ---------------- kernel 3: merge split-KV partials -> y ----------------
__global__ __launch_bounds__(256) void combine_kernel(
    const float* __restrict__ pacc, const float* __restrict__ pml,
    float* __restrict__ y)
{
    const int wid  = threadIdx.x >> 6;
    const int lane = threadIdx.x & 63;
    const int bq   = blockIdx.x * 4 + wid;          // fused b*NN + q
    const int b    = (bq >= NN) ? 1 : 0;
    const int q    = bq - b * NN;

    float mv[SEG], lv[SEG];
    #pragma unroll
    for (int s = 0; s < SEG; ++s) {
        const float* p = pml + ((size_t)(b*SEG + s) * NN + q) * 2;
        mv[s] = p[0];
        lv[s] = p[1];
    }
    float M = mv[0];
    #pragma unroll
    for (int s = 1; s < SEG; ++s) M = fmaxf(M, mv[s]);
    float wsum = 0.f, w[SEG];
    #pragma unroll
    for (int s = 0; s < SEG; ++s) {
        w[s] = __builtin_amdgcn_exp2f(mv[s] - M);
        wsum = fmaf(w[s], lv[s], wsum);
    }
    const float inv = 1.0f / wsum;

    const int ci = lane * 2;
    float a0 = 0.f, a1 = 0.f;
    #pragma unroll
    for (int s = 0; s < SEG; ++s) {
        const float* p = pacc + ((size_t)(b*SEG + s) * NN + q) * CI + ci;
        a0 = fmaf(w[s], p[0], a0);
        a1 = fmaf(w[s], p[1], a1);
    }
    y[(size_t)bq * CI + ci]     = a0 * inv;
    y[(size_t)bq * CI + ci + 1] = a1 * inv;
}

// ---------------- kernel 4: y@Wo + BN(inference) + residual ----------------
__global__ __launch_bounds__(256) void out_kernel(
    const float* __restrict__ x, const float* __restrict__ y,
    const float* __restrict__ Wo, const float* __restrict__ bo,
    const float* __restrict__ gamma, const float* __restrict__ beta,
    const float* __restrict__ mmean, const float* __restrict__ mvar,
    float* __restrict__ out)
{
    __shared__ float ys[16][132];
    const int p0  = blockIdx.x * 16;
    const int tid = threadIdx.x;
    {
        const int pr = tid >> 4, cc0 = (tid & 15) * 8;
        const float* ysrc = y + (size_t)(p0 + pr) * CI + cc0;
        float4 a0 = *reinterpret_cast<const float4*>(ysrc);
        float4 a1 = *reinterpret_cast<const float4*>(ysrc + 4);
        *reinterpret_cast<float4*>(&ys[pr][cc0])     = a0;
        *reinterpret_cast<float4*>(&ys[pr][cc0 + 4]) = a1;
    }
    __syncthreads();

    const int c = tid;
    float a[16];
    #pragma unroll
    for (int p = 0; p < 16; ++p) a[p] = 0.f;
    for (int k = 0; k < CI; ++k) {
        float w = Wo[k * CC + c];
        #pragma unroll
        for (int p = 0; p < 16; ++p)
            a[p] = fmaf(ys[p][k], w, a[p]);
    }
    const float sc = gamma[c] * rsqrtf(mvar[c] + 1e-3f);
    const float sh = beta[c] + sc * (bo[c] - mmean[c]);
    #pragma unroll
    for (int p = 0; p < 16; ++p) {
        size_t idx = (size_t)(p0 + p) * CC + c;
        out[idx] = x[idx] + sc * a[p] + sh;
    }
}

extern "C" void kernel_launch(void* const* d_in, const int* in_sizes, int n_in,
                              void* d_out, int out_size, void* d_ws, size_t ws_size,
                              hipStream_t stream)
{
    const float* x     = (const float*)d_in[0];
    const float* Wg    = (const float*)d_in[1];
    const float* bg    = (const float*)d_in[2];
    const float* Wt    = (const float*)d_in[3];
    const float* bt    = (const float*)d_in[4];
    const float* Wp    = (const float*)d_in[5];
    const float* bp    = (const float*)d_in[6];
    const float* Wo    = (const float*)d_in[7];
    const float* bo    = (const float*)d_in[8];
    const float* gamma = (const float*)d_in[9];
    const float* beta  = (const float*)d_in[10];
    const float* mmean = (const float*)d_in[11];
    const float* mvar  = (const float*)d_in[12];
    float* out = (float*)d_out;

    const size_t PB = (size_t)BB * NN * CI;                 // 1,605,632
    f16*   th   = (f16*)d_ws;                               // 3.2 MB
    f16*   ph   = th + PB;                                  // 3.2 MB
    f16*   gT   = ph + PB;                                  // 3.2 MB
    float* pacc = (float*)(gT + PB);                        // BB*SEG*NN*CI f32 = 45 MB
    float* pml  = pacc + (size_t)BB * SEG * NN * CI;        // 0.7 MB
    float* yv   = pml + (size_t)BB * SEG * NN * 2;          // 6.4 MB

    proj_kernel<<<dim3(BB * NN / 16), 128, 0, stream>>>(x, Wg, bg, Wt, bt, Wp, bp, th, ph, gT);
    attn_kernel<<<dim3(NN / 128, SEG, BB), 256, 0, stream>>>(th, ph, gT, pacc, pml);
    combine_kernel<<<dim3(BB * NN / 4), 256, 0, stream>>>(pacc, pml, yv);
    out_kernel<<<dim3(BB * NN / 16), 256, 0, stream>>>(x, yv, Wo, bo, gamma, beta, mmean, mvar, out);
}

// Round 4
// 233.629 us; speedup vs baseline: 2.8006x; 1.3644x over previous
//
#include <hip/hip_runtime.h>

#define BB 2
#define NN 6272
#define CC 256
#define CI 128
#define SEG 7
#define KVSEG (NN / SEG)          // 896 kv per segment, 28 tiles of 32
#define LOG2E 1.44269504088896f
#define THR 12.0f                 // defer-max threshold (log2 domain), P <= 4096 fits f16

typedef _Float16 f16;
typedef __attribute__((ext_vector_type(2))) __fp16 fp16v2;   // cvt_pkrtz native type
typedef __attribute__((ext_vector_type(8))) _Float16 f16x8;
typedef __attribute__((ext_vector_type(4))) float f32x4;

// ---------------- kernel 1: g/theta/phi projections (fp32 vector, fp16 out) ----------
// th = (x@Wt + bt) * LOG2E   [b][n][ci]   (pre-scaled: softmax in exp2 domain)
// ph = (x@Wp + bp)           [b][n][ci]
// gT = (x@Wg + bg)           [b][ci][n]   (transposed: PV A-fragments)
__global__ __launch_bounds__(128) void proj_kernel(
    const float* __restrict__ x,
    const float* __restrict__ Wg, const float* __restrict__ bg,
    const float* __restrict__ Wt, const float* __restrict__ bt,
    const float* __restrict__ Wp, const float* __restrict__ bp,
    f16* __restrict__ th, f16* __restrict__ ph, f16* __restrict__ gT)
{
    __shared__ float xs[16][257];
    const int p0  = blockIdx.x * 16;
    const int tid = threadIdx.x;

    {
        const int pr = tid >> 3, c0 = (tid & 7) * 32;
        const float* xsrc = x + (size_t)(p0 + pr) * CC + c0;
        #pragma unroll
        for (int i = 0; i < 8; ++i) {
            float4 v = *reinterpret_cast<const float4*>(xsrc + 4 * i);
            xs[pr][c0 + 4*i + 0] = v.x;
            xs[pr][c0 + 4*i + 1] = v.y;
            xs[pr][c0 + 4*i + 2] = v.z;
            xs[pr][c0 + 4*i + 3] = v.w;
        }
    }
    __syncthreads();

    const int ci = tid;
    float ag[16], at[16], ap[16];
    #pragma unroll
    for (int p = 0; p < 16; ++p) { ag[p]=0.f; at[p]=0.f; ap[p]=0.f; }

    for (int c = 0; c < CC; ++c) {
        float wg = Wg[c*CI + ci];
        float wt = Wt[c*CI + ci];
        float wp = Wp[c*CI + ci];
        #pragma unroll
        for (int p = 0; p < 16; ++p) {
            float xv = xs[p][c];
            ag[p] = fmaf(xv, wg, ag[p]);
            at[p] = fmaf(xv, wt, at[p]);
            ap[p] = fmaf(xv, wp, ap[p]);
        }
    }
    const float bgv = bg[ci], btv = bt[ci], bpv = bp[ci];
    const int b  = (p0 >= NN) ? 1 : 0;
    const int n0 = p0 - b * NN;

    f16 gbuf[16];
    #pragma unroll
    for (int p = 0; p < 16; ++p) {
        size_t idx = (size_t)(p0 + p) * CI + ci;
        th[idx] = (f16)((at[p] + btv) * LOG2E);
        ph[idx] = (f16)(ap[p] + bpv);
        gbuf[p] = (f16)(ag[p] + bgv);
    }
    f16* gdst = gT + ((size_t)b * CI + ci) * NN + n0;
    *reinterpret_cast<float4*>(gdst)     = *reinterpret_cast<const float4*>(&gbuf[0]);
    *reinterpret_cast<float4*>(gdst + 8) = *reinterpret_cast<const float4*>(&gbuf[8]);
}

// ---------------- kernel 2: split-KV flash attention, swapped-MFMA layout ------------
// grid (NN/64, SEG, BB); 4 waves/block; wave owns 16 q rows. KV tile = 32.
// S^T = mfma(phi, theta): D col = q (lane&15), row = kv (16t + 4lg + r)
//   -> per-lane softmax state (m scalar), max reduce = 7 fmax + shfl 16,32.
// Y^T = mfma(gT, P^T):    D col = q, row = ci.  Row-sum via all-ones A-frag MFMA.
// phi/g tiles staged once per block in LDS (4x L2 traffic cut); phi XOR-swizzled.
__global__ __launch_bounds__(256, 4) void attn_kernel(
    const f16* __restrict__ th, const f16* __restrict__ ph,
    const f16* __restrict__ gT, float* __restrict__ pacc, float* __restrict__ pml)
{
    __shared__ __align__(16) f16 ph_lds[32 * 128];   // [kv row][c], byte-swizzled
    __shared__ __align__(16) f16 g_lds[128 * 32];    // [ci row][kv]
    __shared__ __align__(16) f16 pT_lds[4][16][40];  // per-wave [q][kv+pad]

    const int b   = blockIdx.z;
    const int seg = blockIdx.y;
    const int tid = threadIdx.x;
    const int wid = tid >> 6;
    const int lane = tid & 63;
    const int l15 = lane & 15;
    const int lg  = lane >> 4;
    const int qw  = blockIdx.x * 64 + wid * 16;

    const f16* thb = th + (size_t)b * NN * CI;
    const f16* phb = ph + (size_t)b * NN * CI;
    const f16* gTb = gT + (size_t)b * CI * NN;

    // persistent theta B-frags (col=q=l15, k = kk*32 + lg*8 + j)
    f16x8 bf[4];
    {
        const f16* trow = thb + (size_t)(qw + l15) * CI + lg * 8;
        #pragma unroll
        for (int kk = 0; kk < 4; ++kk)
            bf[kk] = *reinterpret_cast<const f16x8*>(trow + kk * 32);
    }

    f32x4 acc[8];                 // Y^T: 8 ci-tiles, col=q
    f32x4 accl;                   // row-sum (ones trick)
    float m = -INFINITY;
    #pragma unroll
    for (int ct = 0; ct < 8; ++ct) acc[ct] = (f32x4){0.f,0.f,0.f,0.f};
    accl = (f32x4){0.f,0.f,0.f,0.f};

    const f16x8 onesA = {(f16)1,(f16)1,(f16)1,(f16)1,(f16)1,(f16)1,(f16)1,(f16)1};

    // staging assignments
    const int prow = tid >> 3, pcol = (tid & 7) * 16;   // phi: 32 rows x 128 c
    const int growi = tid >> 1, gcol = (tid & 1) * 16;  // g: 128 rows x 32 kv
    const int pswz = (prow & 7) << 3;                   // phi XOR swizzle (halfs)

    const int kv_base = seg * KVSEG;

    #pragma unroll 1
    for (int it = 0; it < KVSEG / 32; ++it) {
        const int kv0 = kv_base + it * 32;

        // issue global loads early (hide L2 latency under prev compute + barrier)
        const f16* psrc = phb + (size_t)(kv0 + prow) * CI + pcol;
        const f16* gsrc = gTb + (size_t)growi * NN + kv0 + gcol;
        f16x8 pv0 = *reinterpret_cast<const f16x8*>(psrc);
        f16x8 pv1 = *reinterpret_cast<const f16x8*>(psrc + 8);
        f16x8 gv0 = *reinterpret_cast<const f16x8*>(gsrc);
        f16x8 gv1 = *reinterpret_cast<const f16x8*>(gsrc + 8);

        __syncthreads();   // all waves done reading previous tiles
        *reinterpret_cast<f16x8*>(&ph_lds[prow*128 + (pcol ^ pswz)])       = pv0;
        *reinterpret_cast<f16x8*>(&ph_lds[prow*128 + ((pcol + 8) ^ pswz)]) = pv1;
        *reinterpret_cast<f16x8*>(&g_lds[growi*32 + gcol])                 = gv0;
        *reinterpret_cast<f16x8*>(&g_lds[growi*32 + gcol + 8])             = gv1;
        __syncthreads();   // tiles ready

        // ---- S^T = phi @ theta^T : two 16(kv)x16(q) tiles ----
        f32x4 s0 = (f32x4){0.f,0.f,0.f,0.f};
        f32x4 s1 = (f32x4){0.f,0.f,0.f,0.f};
        const int xsw = (l15 & 7) << 3;     // row&7 identical for row and row+16
        #pragma unroll
        for (int kk = 0; kk < 4; ++kk) {
            const int coff = (kk*32 + lg*8) ^ xsw;
            f16x8 a0 = *reinterpret_cast<const f16x8*>(&ph_lds[l15*128 + coff]);
            f16x8 a1 = *reinterpret_cast<const f16x8*>(&ph_lds[(16 + l15)*128 + coff]);
            s0 = __builtin_amdgcn_mfma_f32_16x16x32_f16(a0, bf[kk], s0, 0, 0, 0);
            s1 = __builtin_amdgcn_mfma_f32_16x16x32_f16(a1, bf[kk], s1, 0, 0, 0);
        }

        // ---- online max (lane-local column), defer-rescale ----
        float tm = fmaxf(fmaxf(fmaxf(s0[0], s0[1]), fmaxf(s0[2], s0[3])),
                         fmaxf(fmaxf(s1[0], s1[1]), fmaxf(s1[2], s1[3])));
        tm = fmaxf(tm, __shfl_xor(tm, 16));
        tm = fmaxf(tm, __shfl_xor(tm, 32));
        if (__any(tm > m + THR)) {
            float nm = fmaxf(m, tm);
            float sc = __builtin_amdgcn_exp2f(m - nm);
            m = nm;
            #pragma unroll
            for (int ct = 0; ct < 8; ++ct) {
                acc[ct][0] *= sc; acc[ct][1] *= sc; acc[ct][2] *= sc; acc[ct][3] *= sc;
            }
            accl[0] *= sc; accl[1] *= sc; accl[2] *= sc; accl[3] *= sc;
        }

        // ---- P^T = exp2(S^T - m), pack f16, exchange via per-wave LDS ----
        float p00 = __builtin_amdgcn_exp2f(s0[0] - m);
        float p01 = __builtin_amdgcn_exp2f(s0[1] - m);
        float p02 = __builtin_amdgcn_exp2f(s0[2] - m);
        float p03 = __builtin_amdgcn_exp2f(s0[3] - m);
        float p10 = __builtin_amdgcn_exp2f(s1[0] - m);
        float p11 = __builtin_amdgcn_exp2f(s1[1] - m);
        float p12 = __builtin_amdgcn_exp2f(s1[2] - m);
        float p13 = __builtin_amdgcn_exp2f(s1[3] - m);
        union { fp16v2 h[2]; float2 f; } u0, u1;
        u0.h[0] = __builtin_amdgcn_cvt_pkrtz(p00, p01);
        u0.h[1] = __builtin_amdgcn_cvt_pkrtz(p02, p03);
        u1.h[0] = __builtin_amdgcn_cvt_pkrtz(p10, p11);
        u1.h[1] = __builtin_amdgcn_cvt_pkrtz(p12, p13);
        *reinterpret_cast<float2*>(&pT_lds[wid][l15][4*lg])      = u0.f;
        *reinterpret_cast<float2*>(&pT_lds[wid][l15][16 + 4*lg]) = u1.f;
        asm volatile("s_waitcnt lgkmcnt(0)" ::: "memory");  // intra-wave cross-lane via LDS
        f16x8 pa = *reinterpret_cast<const f16x8*>(&pT_lds[wid][l15][8*lg]);

        // ---- Y^T += gT @ P^T ----
        #pragma unroll
        for (int ct = 0; ct < 8; ++ct) {
            f16x8 ga = *reinterpret_cast<const f16x8*>(&g_lds[(ct*16 + l15)*32 + lg*8]);
            acc[ct] = __builtin_amdgcn_mfma_f32_16x16x32_f16(ga, pa, acc[ct], 0, 0, 0);
        }
        accl = __builtin_amdgcn_mfma_f32_16x16x32_f16(onesA, pa, accl, 0, 0, 0);
    }

    // ---- store partials: pacc[bs][ci][n] (ci-major, coalesced in q) ----
    float* pb = pacc + (size_t)(b*SEG + seg) * CI * NN + qw + l15;
    #pragma unroll
    for (int ct = 0; ct < 8; ++ct)
        #pragma unroll
        for (int r = 0; r < 4; ++r)
            pb[(size_t)(ct*16 + lg*4 + r) * NN] = acc[ct][r];

    if (lg == 0) {
        float* mlb = pml + ((size_t)(b*SEG + seg) * NN + qw + l15) * 2;
        mlb[0] = m;
        mlb[1] = accl[0];
    }
}

// ---------------- kernel 3: merge split-KV partials -> y [pos][ci] ----------------
__global__ __launch_bounds__(256) void combine_kernel(
    const float* __restrict__ pacc, const float* __restrict__ pml,
    float* __restrict__ y)
{
    const int qL = threadIdx.x & 31;
    const int cg = threadIdx.x >> 5;          // 0..7, 16 ci each
    const int q  = blockIdx.x * 32 + qL;
    const int b  = blockIdx.y;

    float mv[SEG], lv[SEG];
    #pragma unroll
    for (int s = 0; s < SEG; ++s) {
        const float* p = pml + ((size_t)(b*SEG + s) * NN + q) * 2;
        mv[s] = p[0];
        lv[s] = p[1];
    }
    float M = mv[0];
    #pragma unroll
    for (int s = 1; s < SEG; ++s) M = fmaxf(M, mv[s]);
    float wsum = 0.f, w[SEG];
    #pragma unroll
    for (int s = 0; s < SEG; ++s) {
        w[s] = __builtin_amdgcn_exp2f(mv[s] - M);
        wsum = fmaf(w[s], lv[s], wsum);
    }
    const float inv = 1.0f / wsum;

    const int c0 = cg * 16;
    float o[16];
    #pragma unroll
    for (int i = 0; i < 16; ++i) o[i] = 0.f;
    for (int s = 0; s < SEG; ++s) {
        const float* pb = pacc + ((size_t)(b*SEG + s) * CI + c0) * NN + q;
        #pragma unroll
        for (int i = 0; i < 16; ++i)
            o[i] = fmaf(w[s], pb[(size_t)i * NN], o[i]);
    }
    float* yo = y + ((size_t)b * NN + q) * CI + c0;
    #pragma unroll
    for (int i = 0; i < 4; ++i) {
        float4 v = make_float4(o[4*i]*inv, o[4*i+1]*inv, o[4*i+2]*inv, o[4*i+3]*inv);
        *reinterpret_cast<float4*>(yo + 4*i) = v;
    }
}

// ---------------- kernel 4: y@Wo + BN(inference) + residual ----------------
__global__ __launch_bounds__(256) void out_kernel(
    const float* __restrict__ x, const float* __restrict__ y,
    const float* __restrict__ Wo, const float* __restrict__ bo,
    const float* __restrict__ gamma, const float* __restrict__ beta,
    const float* __restrict__ mmean, const float* __restrict__ mvar,
    float* __restrict__ out)
{
    __shared__ float ys[16][132];
    const int p0  = blockIdx.x * 16;
    const int tid = threadIdx.x;
    {
        const int pr = tid >> 4, cc0 = (tid & 15) * 8;
        const float* ysrc = y + (size_t)(p0 + pr) * CI + cc0;
        float4 a0 = *reinterpret_cast<const float4*>(ysrc);
        float4 a1 = *reinterpret_cast<const float4*>(ysrc + 4);
        *reinterpret_cast<float4*>(&ys[pr][cc0])     = a0;
        *reinterpret_cast<float4*>(&ys[pr][cc0 + 4]) = a1;
    }
    __syncthreads();

    const int c = tid;
    float a[16];
    #pragma unroll
    for (int p = 0; p < 16; ++p) a[p] = 0.f;
    for (int k = 0; k < CI; ++k) {
        float w = Wo[k * CC + c];
        #pragma unroll
        for (int p = 0; p < 16; ++p)
            a[p] = fmaf(ys[p][k], w, a[p]);
    }
    const float sc = gamma[c] * rsqrtf(mvar[c] + 1e-3f);
    const float sh = beta[c] + sc * (bo[c] - mmean[c]);
    #pragma unroll
    for (int p = 0; p < 16; ++p) {
        size_t idx = (size_t)(p0 + p) * CC + c;
        out[idx] = x[idx] + sc * a[p] + sh;
    }
}

extern "C" void kernel_launch(void* const* d_in, const int* in_sizes, int n_in,
                              void* d_out, int out_size, void* d_ws, size_t ws_size,
                              hipStream_t stream)
{
    const float* x     = (const float*)d_in[0];
    const float* Wg    = (const float*)d_in[1];
    const float* bg    = (const float*)d_in[2];
    const float* Wt    = (const float*)d_in[3];
    const float* bt    = (const float*)d_in[4];
    const float* Wp    = (const float*)d_in[5];
    const float* bp    = (const float*)d_in[6];
    const float* Wo    = (const float*)d_in[7];
    const float* bo    = (const float*)d_in[8];
    const float* gamma = (const float*)d_in[9];
    const float* beta  = (const float*)d_in[10];
    const float* mmean = (const float*)d_in[11];
    const float* mvar  = (const float*)d_in[12];
    float* out = (float*)d_out;

    const size_t PB = (size_t)BB * NN * CI;                 // 1,605,632
    f16*   th   = (f16*)d_ws;                               // 3.2 MB
    f16*   ph   = th + PB;                                  // 3.2 MB
    f16*   gT   = ph + PB;                                  // 3.2 MB
    float* pacc = (float*)(gT + PB);                        // 45 MB [bs][ci][n]
    float* pml  = pacc + (size_t)BB * SEG * NN * CI;        // 0.7 MB
    float* yv   = pml + (size_t)BB * SEG * NN * 2;          // 6.4 MB

    proj_kernel<<<dim3(BB * NN / 16), 128, 0, stream>>>(x, Wg, bg, Wt, bt, Wp, bp, th, ph, gT);
    attn_kernel<<<dim3(NN / 64, SEG, BB), 256, 0, stream>>>(th, ph, gT, pacc, pml);
    combine_kernel<<<dim3(NN / 32, BB), 256, 0, stream>>>(pacc, pml, yv);
    out_kernel<<<dim3(BB * NN / 16), 256, 0, stream>>>(x, yv, Wo, bo, gamma, beta, mmean, mvar, out);
}

// Round 5
// 140.611 us; speedup vs baseline: 4.6533x; 1.6615x over previous
//
#include <hip/hip_runtime.h>

#define BB 2
#define NN 6272
#define CC 256
#define CI 128
#define SEG 7
#define KVSEG (NN / SEG)          // 896 kv per segment, 28 tiles of 32
#define LOG2E 1.44269504088896f
#define THR 12.0f                 // defer-max threshold (log2 domain), P <= 4096 fits f16

typedef _Float16 f16;
typedef __attribute__((ext_vector_type(2))) __fp16 fp16v2;   // cvt_pkrtz native type
typedef __attribute__((ext_vector_type(8))) _Float16 f16x8;
typedef __attribute__((ext_vector_type(4))) float f32x4;

// ---------------- kernel 0: weight prep (once, ~3us) ----------------
// WallT[j][k] f16, j in [0,384): j<128 -> Wg col j; j<256 -> Wt*LOG2E; else Wp.
// WoT[ci][k] f16 = Wo[k][ci].  ball[384] fused biases.  bnsc/bnsh BN scale/shift.
__global__ __launch_bounds__(256) void prep_kernel(
    const float* __restrict__ Wg, const float* __restrict__ Wt, const float* __restrict__ Wp,
    const float* __restrict__ Wo, const float* __restrict__ bg, const float* __restrict__ bt,
    const float* __restrict__ bp, const float* __restrict__ bo,
    const float* __restrict__ gamma, const float* __restrict__ beta,
    const float* __restrict__ mmean, const float* __restrict__ mvar,
    f16* __restrict__ WallT, f16* __restrict__ WoT,
    float* __restrict__ ball, float* __restrict__ bnsc, float* __restrict__ bnsh)
{
    const int idx = blockIdx.x * 256 + threadIdx.x;
    if (idx < 384*256) {
        const int j = idx >> 8, k = idx & 255;
        float v;
        if (j < 128)      v = Wg[k*CI + j];
        else if (j < 256) v = Wt[k*CI + (j-128)] * LOG2E;
        else              v = Wp[k*CI + (j-256)];
        WallT[j*256 + k] = (f16)v;
    } else if (idx < 384*256 + 256*128) {
        const int i2 = idx - 384*256;
        const int ci = i2 >> 7, k = i2 & 127;
        WoT[ci*CI + k] = (f16)Wo[k*CC + ci];
    } else {
        const int i3 = idx - (384*256 + 256*128);
        if (i3 < 384) {
            float v;
            if (i3 < 128)      v = bg[i3];
            else if (i3 < 256) v = bt[i3-128] * LOG2E;
            else               v = bp[i3-256];
            ball[i3] = v;
        } else if (i3 < 640) {
            const int c = i3 - 384;
            bnsc[c] = gamma[c] * rsqrtf(mvar[c] + 1e-3f);
        } else if (i3 < 896) {
            const int c = i3 - 640;
            float sc = gamma[c] * rsqrtf(mvar[c] + 1e-3f);
            bnsh[c] = beta[c] + sc * (bo[c] - mmean[c]);
        }
    }
}

// ---------------- kernel 1: fused projection GEMM (MFMA) ----------------
// [16 pos] x [256 k] x [384 j] per block; 4 waves, wave nq owns 96 j (6 n-tiles).
// A-frags from LDS x-tile (f16, pad 264); B-frags direct from L2-resident WallT.
// Epilogue: j<128 -> gT via LDS transpose; 128..255 -> th; 256.. -> ph.
__global__ __launch_bounds__(256) void proj_gemm(
    const float* __restrict__ x, const f16* __restrict__ WallT, const float* __restrict__ ball,
    f16* __restrict__ th, f16* __restrict__ ph, f16* __restrict__ gT)
{
    __shared__ __align__(16) f16 xls[16*264];
    __shared__ __align__(16) f16 gls[128*24];

    const int tid = threadIdx.x;
    const int wid = tid >> 6, lane = tid & 63;
    const int l15 = lane & 15, lg = lane >> 4;
    const int p0 = blockIdx.x * 16;
    const int nq = wid;

    {   // stage x tile 16x256 -> f16 LDS
        const int row = tid >> 4, seg = (tid & 15) * 16;
        const float* xsrc = x + (size_t)(p0 + row) * CC + seg;
        f16 buf[16];
        #pragma unroll
        for (int i = 0; i < 4; ++i) {
            float4 v = *reinterpret_cast<const float4*>(xsrc + 4*i);
            buf[4*i+0]=(f16)v.x; buf[4*i+1]=(f16)v.y; buf[4*i+2]=(f16)v.z; buf[4*i+3]=(f16)v.w;
        }
        *reinterpret_cast<f16x8*>(&xls[row*264 + seg])     = *reinterpret_cast<f16x8*>(&buf[0]);
        *reinterpret_cast<f16x8*>(&xls[row*264 + seg + 8]) = *reinterpret_cast<f16x8*>(&buf[8]);
    }
    __syncthreads();

    f32x4 acc[6];
    #pragma unroll
    for (int t = 0; t < 6; ++t) acc[t] = (f32x4){0.f,0.f,0.f,0.f};

    const f16* wbase = WallT + (size_t)(nq*96 + l15)*256 + lg*8;
    for (int kk = 0; kk < 8; ++kk) {
        f16x8 a = *reinterpret_cast<const f16x8*>(&xls[l15*264 + kk*32 + lg*8]);
        #pragma unroll
        for (int t = 0; t < 6; ++t) {
            f16x8 bfr = *reinterpret_cast<const f16x8*>(wbase + (size_t)t*16*256 + kk*32);
            acc[t] = __builtin_amdgcn_mfma_f32_16x16x32_f16(a, bfr, acc[t], 0, 0, 0);
        }
    }

    const int bidx = (p0 >= NN) ? 1 : 0;
    const int n0 = p0 - bidx * NN;
    const int prow = lg * 4;

    #pragma unroll
    for (int t = 0; t < 6; ++t) {
        const int j0 = nq*96 + t*16;          // + l15 per lane
        const float bv = ball[j0 + l15];
        if (j0 < 128) {          // g -> LDS transpose
            #pragma unroll
            for (int r = 0; r < 4; ++r)
                gls[(j0 + l15)*24 + prow + r] = (f16)(acc[t][r] + bv);
        } else if (j0 < 256) {   // theta (pre-scaled)
            f16* dst = th + (size_t)(p0 + prow)*CI + (j0 - 128) + l15;
            #pragma unroll
            for (int r = 0; r < 4; ++r)
                dst[(size_t)r*CI] = (f16)(acc[t][r] + bv);
        } else {                 // phi
            f16* dst = ph + (size_t)(p0 + prow)*CI + (j0 - 256) + l15;
            #pragma unroll
            for (int r = 0; r < 4; ++r)
                dst[(size_t)r*CI] = (f16)(acc[t][r] + bv);
        }
    }
    __syncthreads();
    {   // contiguous gT store
        const int ci = tid >> 1, part = tid & 1;
        f16x8 v = *reinterpret_cast<const f16x8*>(&gls[ci*24 + part*8]);
        f16* gdst = gT + ((size_t)bidx*CI + ci)*NN + n0 + part*8;
        *reinterpret_cast<f16x8*>(gdst) = v;
    }
}

// ---------------- kernel 2: split-KV flash attention, swapped-MFMA layout ------------
__global__ __launch_bounds__(256, 4) void attn_kernel(
    const f16* __restrict__ th, const f16* __restrict__ ph,
    const f16* __restrict__ gT, float* __restrict__ pacc, float* __restrict__ pml)
{
    __shared__ __align__(16) f16 ph_lds[32 * 128];   // [kv row][c], byte-swizzled
    __shared__ __align__(16) f16 g_lds[128 * 32];    // [ci row][kv]
    __shared__ __align__(16) f16 pT_lds[4][16][40];  // per-wave [q][kv+pad]

    const int b   = blockIdx.z;
    const int seg = blockIdx.y;
    const int tid = threadIdx.x;
    const int wid = tid >> 6;
    const int lane = tid & 63;
    const int l15 = lane & 15;
    const int lg  = lane >> 4;
    const int qw  = blockIdx.x * 64 + wid * 16;

    const f16* thb = th + (size_t)b * NN * CI;
    const f16* phb = ph + (size_t)b * NN * CI;
    const f16* gTb = gT + (size_t)b * CI * NN;

    // persistent theta B-frags (col=q=l15, k = kk*32 + lg*8 + j)
    f16x8 bf[4];
    {
        const f16* trow = thb + (size_t)(qw + l15) * CI + lg * 8;
        #pragma unroll
        for (int kk = 0; kk < 4; ++kk)
            bf[kk] = *reinterpret_cast<const f16x8*>(trow + kk * 32);
    }

    f32x4 acc[8];                 // Y^T: 8 ci-tiles, col=q
    f32x4 accl;                   // row-sum (ones trick)
    float m = -INFINITY;
    #pragma unroll
    for (int ct = 0; ct < 8; ++ct) acc[ct] = (f32x4){0.f,0.f,0.f,0.f};
    accl = (f32x4){0.f,0.f,0.f,0.f};

    const f16x8 onesA = {(f16)1,(f16)1,(f16)1,(f16)1,(f16)1,(f16)1,(f16)1,(f16)1};

    const int prow = tid >> 3, pcol = (tid & 7) * 16;   // phi: 32 rows x 128 c
    const int growi = tid >> 1, gcol = (tid & 1) * 16;  // g: 128 rows x 32 kv
    const int pswz = (prow & 7) << 3;                   // phi XOR swizzle (halfs)

    const int kv_base = seg * KVSEG;

    #pragma unroll 1
    for (int it = 0; it < KVSEG / 32; ++it) {
        const int kv0 = kv_base + it * 32;

        const f16* psrc = phb + (size_t)(kv0 + prow) * CI + pcol;
        const f16* gsrc = gTb + (size_t)growi * NN + kv0 + gcol;
        f16x8 pv0 = *reinterpret_cast<const f16x8*>(psrc);
        f16x8 pv1 = *reinterpret_cast<const f16x8*>(psrc + 8);
        f16x8 gv0 = *reinterpret_cast<const f16x8*>(gsrc);
        f16x8 gv1 = *reinterpret_cast<const f16x8*>(gsrc + 8);

        __syncthreads();
        *reinterpret_cast<f16x8*>(&ph_lds[prow*128 + (pcol ^ pswz)])       = pv0;
        *reinterpret_cast<f16x8*>(&ph_lds[prow*128 + ((pcol + 8) ^ pswz)]) = pv1;
        *reinterpret_cast<f16x8*>(&g_lds[growi*32 + gcol])                 = gv0;
        *reinterpret_cast<f16x8*>(&g_lds[growi*32 + gcol + 8])             = gv1;
        __syncthreads();

        // ---- S^T = phi @ theta^T ----
        f32x4 s0 = (f32x4){0.f,0.f,0.f,0.f};
        f32x4 s1 = (f32x4){0.f,0.f,0.f,0.f};
        const int xsw = (l15 & 7) << 3;
        #pragma unroll
        for (int kk = 0; kk < 4; ++kk) {
            const int coff = (kk*32 + lg*8) ^ xsw;
            f16x8 a0 = *reinterpret_cast<const f16x8*>(&ph_lds[l15*128 + coff]);
            f16x8 a1 = *reinterpret_cast<const f16x8*>(&ph_lds[(16 + l15)*128 + coff]);
            s0 = __builtin_amdgcn_mfma_f32_16x16x32_f16(a0, bf[kk], s0, 0, 0, 0);
            s1 = __builtin_amdgcn_mfma_f32_16x16x32_f16(a1, bf[kk], s1, 0, 0, 0);
        }

        // ---- online max, defer-rescale ----
        float tm = fmaxf(fmaxf(fmaxf(s0[0], s0[1]), fmaxf(s0[2], s0[3])),
                         fmaxf(fmaxf(s1[0], s1[1]), fmaxf(s1[2], s1[3])));
        tm = fmaxf(tm, __shfl_xor(tm, 16));
        tm = fmaxf(tm, __shfl_xor(tm, 32));
        if (__any(tm > m + THR)) {
            float nm = fmaxf(m, tm);
            float sc = __builtin_amdgcn_exp2f(m - nm);
            m = nm;
            #pragma unroll
            for (int ct = 0; ct < 8; ++ct) {
                acc[ct][0] *= sc; acc[ct][1] *= sc; acc[ct][2] *= sc; acc[ct][3] *= sc;
            }
            accl[0] *= sc; accl[1] *= sc; accl[2] *= sc; accl[3] *= sc;
        }

        // ---- P^T = exp2(S^T - m), pack f16, exchange via per-wave LDS ----
        float p00 = __builtin_amdgcn_exp2f(s0[0] - m);
        float p01 = __builtin_amdgcn_exp2f(s0[1] - m);
        float p02 = __builtin_amdgcn_exp2f(s0[2] - m);
        float p03 = __builtin_amdgcn_exp2f(s0[3] - m);
        float p10 = __builtin_amdgcn_exp2f(s1[0] - m);
        float p11 = __builtin_amdgcn_exp2f(s1[1] - m);
        float p12 = __builtin_amdgcn_exp2f(s1[2] - m);
        float p13 = __builtin_amdgcn_exp2f(s1[3] - m);
        union { fp16v2 h[2]; float2 f; } u0, u1;
        u0.h[0] = __builtin_amdgcn_cvt_pkrtz(p00, p01);
        u0.h[1] = __builtin_amdgcn_cvt_pkrtz(p02, p03);
        u1.h[0] = __builtin_amdgcn_cvt_pkrtz(p10, p11);
        u1.h[1] = __builtin_amdgcn_cvt_pkrtz(p12, p13);
        *reinterpret_cast<float2*>(&pT_lds[wid][l15][4*lg])      = u0.f;
        *reinterpret_cast<float2*>(&pT_lds[wid][l15][16 + 4*lg]) = u1.f;
        asm volatile("s_waitcnt lgkmcnt(0)" ::: "memory");
        f16x8 pa = *reinterpret_cast<const f16x8*>(&pT_lds[wid][l15][8*lg]);

        // ---- Y^T += gT @ P^T ----
        #pragma unroll
        for (int ct = 0; ct < 8; ++ct) {
            f16x8 ga = *reinterpret_cast<const f16x8*>(&g_lds[(ct*16 + l15)*32 + lg*8]);
            acc[ct] = __builtin_amdgcn_mfma_f32_16x16x32_f16(ga, pa, acc[ct], 0, 0, 0);
        }
        accl = __builtin_amdgcn_mfma_f32_16x16x32_f16(onesA, pa, accl, 0, 0, 0);
    }

    float* pb = pacc + (size_t)(b*SEG + seg) * CI * NN + qw + l15;
    #pragma unroll
    for (int ct = 0; ct < 8; ++ct)
        #pragma unroll
        for (int r = 0; r < 4; ++r)
            pb[(size_t)(ct*16 + lg*4 + r) * NN] = acc[ct][r];

    if (lg == 0) {
        float* mlb = pml + ((size_t)(b*SEG + seg) * NN + qw + l15) * 2;
        mlb[0] = m;
        mlb[1] = accl[0];
    }
}

// ---------------- kernel 3: merge split-KV partials -> yh (f16 [pos][ci]) -----------
__global__ __launch_bounds__(256) void combine_kernel(
    const float* __restrict__ pacc, const float* __restrict__ pml,
    f16* __restrict__ yh)
{
    const int qL = threadIdx.x & 31;
    const int cg = threadIdx.x >> 5;          // 0..7, 16 ci each
    const int q  = blockIdx.x * 32 + qL;
    const int b  = blockIdx.y;

    float mv[SEG], lv[SEG];
    #pragma unroll
    for (int s = 0; s < SEG; ++s) {
        const float* p = pml + ((size_t)(b*SEG + s) * NN + q) * 2;
        mv[s] = p[0];
        lv[s] = p[1];
    }
    float M = mv[0];
    #pragma unroll
    for (int s = 1; s < SEG; ++s) M = fmaxf(M, mv[s]);
    float wsum = 0.f, w[SEG];
    #pragma unroll
    for (int s = 0; s < SEG; ++s) {
        w[s] = __builtin_amdgcn_exp2f(mv[s] - M);
        wsum = fmaf(w[s], lv[s], wsum);
    }
    const float inv = 1.0f / wsum;

    const int c0 = cg * 16;
    float o[16];
    #pragma unroll
    for (int i = 0; i < 16; ++i) o[i] = 0.f;
    for (int s = 0; s < SEG; ++s) {
        const float* pb = pacc + ((size_t)(b*SEG + s) * CI + c0) * NN + q;
        #pragma unroll
        for (int i = 0; i < 16; ++i)
            o[i] = fmaf(w[s], pb[(size_t)i * NN], o[i]);
    }
    f16 oh[16];
    #pragma unroll
    for (int i = 0; i < 16; ++i) oh[i] = (f16)(o[i] * inv);
    f16* yo = yh + ((size_t)b * NN + q) * CI + c0;
    *reinterpret_cast<f16x8*>(yo)     = *reinterpret_cast<f16x8*>(&oh[0]);
    *reinterpret_cast<f16x8*>(yo + 8) = *reinterpret_cast<f16x8*>(&oh[8]);
}

// ---------------- kernel 4: out GEMM (MFMA) + BN + residual ----------------
// [16 pos] x [128 k] x [256 ci]; 4 waves, wave nq owns 64 ci (4 n-tiles).
// A-frags direct from global yh; B-frags direct from L2-resident WoT. No LDS.
__global__ __launch_bounds__(256) void out_gemm(
    const float* __restrict__ x, const f16* __restrict__ yh, const f16* __restrict__ WoT,
    const float* __restrict__ bnsc, const float* __restrict__ bnsh, float* __restrict__ out)
{
    const int tid = threadIdx.x;
    const int wid = tid >> 6, lane = tid & 63;
    const int l15 = lane & 15, lg = lane >> 4;
    const int p0 = blockIdx.x * 16;
    const int nq = wid;

    f32x4 acc[4];
    #pragma unroll
    for (int t = 0; t < 4; ++t) acc[t] = (f32x4){0.f,0.f,0.f,0.f};

    const f16* ya = yh + (size_t)(p0 + l15)*CI + lg*8;
    const f16* wb = WoT + (size_t)(nq*64 + l15)*CI + lg*8;
    #pragma unroll
    for (int kk = 0; kk < 4; ++kk) {
        f16x8 a = *reinterpret_cast<const f16x8*>(ya + kk*32);
        #pragma unroll
        for (int t = 0; t < 4; ++t) {
            f16x8 bfr = *reinterpret_cast<const f16x8*>(wb + (size_t)t*16*CI + kk*32);
            acc[t] = __builtin_amdgcn_mfma_f32_16x16x32_f16(a, bfr, acc[t], 0, 0, 0);
        }
    }

    #pragma unroll
    for (int t = 0; t < 4; ++t) {
        const int ci = nq*64 + t*16 + l15;
        const float sc = bnsc[ci], sh = bnsh[ci];
        #pragma unroll
        for (int r = 0; r < 4; ++r) {
            const size_t idx = (size_t)(p0 + lg*4 + r)*CC + ci;
            out[idx] = x[idx] + fmaf(sc, acc[t][r], sh);
        }
    }
}

extern "C" void kernel_launch(void* const* d_in, const int* in_sizes, int n_in,
                              void* d_out, int out_size, void* d_ws, size_t ws_size,
                              hipStream_t stream)
{
    const float* x     = (const float*)d_in[0];
    const float* Wg    = (const float*)d_in[1];
    const float* bg    = (const float*)d_in[2];
    const float* Wt    = (const float*)d_in[3];
    const float* bt    = (const float*)d_in[4];
    const float* Wp    = (const float*)d_in[5];
    const float* bp    = (const float*)d_in[6];
    const float* Wo    = (const float*)d_in[7];
    const float* bo    = (const float*)d_in[8];
    const float* gamma = (const float*)d_in[9];
    const float* beta  = (const float*)d_in[10];
    const float* mmean = (const float*)d_in[11];
    const float* mvar  = (const float*)d_in[12];
    float* out = (float*)d_out;

    const size_t PB = (size_t)BB * NN * CI;                 // 1,605,632
    f16*   th   = (f16*)d_ws;                               // 3.2 MB
    f16*   ph   = th + PB;                                  // 3.2 MB
    f16*   gT   = ph + PB;                                  // 3.2 MB
    float* pacc = (float*)(gT + PB);                        // 45 MB [bs][ci][n]
    float* pml  = pacc + (size_t)BB * SEG * NN * CI;        // 0.7 MB
    f16*   yh   = (f16*)(pml + (size_t)BB * SEG * NN * 2);  // 3.2 MB
    f16*   WallT= yh + PB;                                  // 197 KB
    f16*   WoT  = WallT + 384*256;                          // 66 KB
    float* ball = (float*)(WoT + 256*CI);                   // 1.5 KB
    float* bnsc = ball + 384;
    float* bnsh = bnsc + 256;

    prep_kernel<<<516, 256, 0, stream>>>(Wg, Wt, Wp, Wo, bg, bt, bp, bo,
                                         gamma, beta, mmean, mvar,
                                         WallT, WoT, ball, bnsc, bnsh);
    proj_gemm<<<BB * NN / 16, 256, 0, stream>>>(x, WallT, ball, th, ph, gT);
    attn_kernel<<<dim3(NN / 64, SEG, BB), 256, 0, stream>>>(th, ph, gT, pacc, pml);
    combine_kernel<<<dim3(NN / 32, BB), 256, 0, stream>>>(pacc, pml, yh);
    out_gemm<<<BB * NN / 16, 256, 0, stream>>>(x, yh, WoT, bnsc, bnsh, out);
}

// Round 6
// 114.676 us; speedup vs baseline: 5.7057x; 1.2262x over previous
//
#include <hip/hip_runtime.h>

#define BB 2
#define NN 6272
#define CC 256
#define CI 128
#define SEG 7
#define KVSEG (NN / SEG)          // 896 kv per segment, 28 tiles of 32
#define LOG2E 1.44269504088896f
#define THR 12.0f                 // defer-max threshold (log2 domain), P <= 4096 fits f16

typedef _Float16 f16;
typedef __attribute__((ext_vector_type(2))) __fp16 fp16v2;   // cvt_pkrtz native type
typedef __attribute__((ext_vector_type(8))) _Float16 f16x8;
typedef __attribute__((ext_vector_type(4))) float f32x4;

// ---------------- kernel 0: weight prep (once, ~3us) ----------------
__global__ __launch_bounds__(256) void prep_kernel(
    const float* __restrict__ Wg, const float* __restrict__ Wt, const float* __restrict__ Wp,
    const float* __restrict__ Wo, const float* __restrict__ bg, const float* __restrict__ bt,
    const float* __restrict__ bp, const float* __restrict__ bo,
    const float* __restrict__ gamma, const float* __restrict__ beta,
    const float* __restrict__ mmean, const float* __restrict__ mvar,
    f16* __restrict__ WallT, f16* __restrict__ WoT,
    float* __restrict__ ball, float* __restrict__ bnsc, float* __restrict__ bnsh)
{
    const int idx = blockIdx.x * 256 + threadIdx.x;
    if (idx < 384*256) {
        const int j = idx >> 8, k = idx & 255;
        float v;
        if (j < 128)      v = Wg[k*CI + j];
        else if (j < 256) v = Wt[k*CI + (j-128)] * LOG2E;
        else              v = Wp[k*CI + (j-256)];
        WallT[j*256 + k] = (f16)v;
    } else if (idx < 384*256 + 256*128) {
        const int i2 = idx - 384*256;
        const int ci = i2 >> 7, k = i2 & 127;
        WoT[ci*CI + k] = (f16)Wo[k*CC + ci];
    } else {
        const int i3 = idx - (384*256 + 256*128);
        if (i3 < 384) {
            float v;
            if (i3 < 128)      v = bg[i3];
            else if (i3 < 256) v = bt[i3-128] * LOG2E;
            else               v = bp[i3-256];
            ball[i3] = v;
        } else if (i3 < 640) {
            const int c = i3 - 384;
            bnsc[c] = gamma[c] * rsqrtf(mvar[c] + 1e-3f);
        } else if (i3 < 896) {
            const int c = i3 - 640;
            float sc = gamma[c] * rsqrtf(mvar[c] + 1e-3f);
            bnsh[c] = beta[c] + sc * (bo[c] - mmean[c]);
        }
    }
}

// ---------------- kernel 1: fused projection GEMM (MFMA) ----------------
__global__ __launch_bounds__(256) void proj_gemm(
    const float* __restrict__ x, const f16* __restrict__ WallT, const float* __restrict__ ball,
    f16* __restrict__ th, f16* __restrict__ ph, f16* __restrict__ gT)
{
    __shared__ __align__(16) f16 xls[16*264];
    __shared__ __align__(16) f16 gls[128*24];

    const int tid = threadIdx.x;
    const int wid = tid >> 6, lane = tid & 63;
    const int l15 = lane & 15, lg = lane >> 4;
    const int p0 = blockIdx.x * 16;
    const int nq = wid;

    {   // stage x tile 16x256 -> f16 LDS
        const int row = tid >> 4, seg = (tid & 15) * 16;
        const float* xsrc = x + (size_t)(p0 + row) * CC + seg;
        f16 buf[16];
        #pragma unroll
        for (int i = 0; i < 4; ++i) {
            float4 v = *reinterpret_cast<const float4*>(xsrc + 4*i);
            buf[4*i+0]=(f16)v.x; buf[4*i+1]=(f16)v.y; buf[4*i+2]=(f16)v.z; buf[4*i+3]=(f16)v.w;
        }
        *reinterpret_cast<f16x8*>(&xls[row*264 + seg])     = *reinterpret_cast<f16x8*>(&buf[0]);
        *reinterpret_cast<f16x8*>(&xls[row*264 + seg + 8]) = *reinterpret_cast<f16x8*>(&buf[8]);
    }
    __syncthreads();

    f32x4 acc[6];
    #pragma unroll
    for (int t = 0; t < 6; ++t) acc[t] = (f32x4){0.f,0.f,0.f,0.f};

    const f16* wbase = WallT + (size_t)(nq*96 + l15)*256 + lg*8;
    for (int kk = 0; kk < 8; ++kk) {
        f16x8 a = *reinterpret_cast<const f16x8*>(&xls[l15*264 + kk*32 + lg*8]);
        #pragma unroll
        for (int t = 0; t < 6; ++t) {
            f16x8 bfr = *reinterpret_cast<const f16x8*>(wbase + (size_t)t*16*256 + kk*32);
            acc[t] = __builtin_amdgcn_mfma_f32_16x16x32_f16(a, bfr, acc[t], 0, 0, 0);
        }
    }

    const int bidx = (p0 >= NN) ? 1 : 0;
    const int n0 = p0 - bidx * NN;
    const int prow = lg * 4;

    #pragma unroll
    for (int t = 0; t < 6; ++t) {
        const int j0 = nq*96 + t*16;          // + l15 per lane
        const float bv = ball[j0 + l15];
        if (j0 < 128) {          // g -> LDS transpose
            #pragma unroll
            for (int r = 0; r < 4; ++r)
                gls[(j0 + l15)*24 + prow + r] = (f16)(acc[t][r] + bv);
        } else if (j0 < 256) {   // theta (pre-scaled)
            f16* dst = th + (size_t)(p0 + prow)*CI + (j0 - 128) + l15;
            #pragma unroll
            for (int r = 0; r < 4; ++r)
                dst[(size_t)r*CI] = (f16)(acc[t][r] + bv);
        } else {                 // phi
            f16* dst = ph + (size_t)(p0 + prow)*CI + (j0 - 256) + l15;
            #pragma unroll
            for (int r = 0; r < 4; ++r)
                dst[(size_t)r*CI] = (f16)(acc[t][r] + bv);
        }
    }
    __syncthreads();
    {   // contiguous gT store
        const int ci = tid >> 1, part = tid & 1;
        f16x8 v = *reinterpret_cast<const f16x8*>(&gls[ci*24 + part*8]);
        f16* gdst = gT + ((size_t)bidx*CI + ci)*NN + n0 + part*8;
        *reinterpret_cast<f16x8*>(gdst) = v;
    }
}

// ---------------- kernel 2: split-KV flash attention, swapped-MFMA layout ------------
// grid (NN/128, SEG, BB); 4 waves/block; wave owns 32 q rows (2 q-tiles). KV tile = 32.
// S^T = mfma(phi, theta): col = q, row = kv -> lane-local softmax column.
// Y^T = mfma(gT, P^T):    col = q, row = ci. Row-sum via all-ones A-frag MFMA.
// phi/g staged per block; BOTH XOR-swizzled for conflict-free quarter-wave access:
//   phi: c ^= (row&7)<<3  (granule = (kk*4+lg) ^ (l15&7) -> 2 lanes/quad)
//   g:   c ^= ((row>>1)&3)<<3 (granule = 4(l15&1) + (lg^((l15>>1)&3)) -> 2 lanes/quad)
__global__ __launch_bounds__(256, 3) void attn_kernel(
    const f16* __restrict__ th, const f16* __restrict__ ph,
    const f16* __restrict__ gT, float* __restrict__ pacc, float* __restrict__ pml)
{
    __shared__ __align__(16) f16 ph_lds[32 * 128];     // [kv][c], swizzled
    __shared__ __align__(16) f16 g_lds[128 * 32];      // [ci][kv], swizzled
    __shared__ __align__(16) f16 pT_lds[4][2][16][40]; // per-wave [qt][q][kv+pad]

    const int b   = blockIdx.z;
    const int seg = blockIdx.y;
    const int tid = threadIdx.x;
    const int wid = tid >> 6;
    const int lane = tid & 63;
    const int l15 = lane & 15;
    const int lg  = lane >> 4;
    const int qw  = blockIdx.x * 128 + wid * 32;

    const f16* thb = th + (size_t)b * NN * CI;
    const f16* phb = ph + (size_t)b * NN * CI;
    const f16* gTb = gT + (size_t)b * CI * NN;

    // persistent theta B-frags: 2 q-tiles x 4 k-frags
    f16x8 bf[2][4];
    #pragma unroll
    for (int qt = 0; qt < 2; ++qt) {
        const f16* trow = thb + (size_t)(qw + qt*16 + l15) * CI + lg * 8;
        #pragma unroll
        for (int kk = 0; kk < 4; ++kk)
            bf[qt][kk] = *reinterpret_cast<const f16x8*>(trow + kk * 32);
    }

    f32x4 acc[2][8];              // Y^T: per q-tile, 8 ci-tiles, col=q
    f32x4 accl[2];                // row-sums (ones trick)
    float m[2] = {-INFINITY, -INFINITY};
    #pragma unroll
    for (int qt = 0; qt < 2; ++qt) {
        #pragma unroll
        for (int ct = 0; ct < 8; ++ct) acc[qt][ct] = (f32x4){0.f,0.f,0.f,0.f};
        accl[qt] = (f32x4){0.f,0.f,0.f,0.f};
    }

    const f16x8 onesA = {(f16)1,(f16)1,(f16)1,(f16)1,(f16)1,(f16)1,(f16)1,(f16)1};

    // staging assignments
    const int prow = tid >> 3, pcol = (tid & 7) * 16;   // phi: 32 rows x 128 c
    const int pswz = (prow & 7) << 3;
    const int growi = tid >> 1, gcol = (tid & 1) * 16;  // g: 128 rows x 32 kv
    const int gswz = ((growi >> 1) & 3) << 3;
    const int gc0 = gcol ^ gswz, gc1 = (gcol + 8) ^ gswz;

    const int kv_base = seg * KVSEG;

    #pragma unroll 1
    for (int it = 0; it < KVSEG / 32; ++it) {
        const int kv0 = kv_base + it * 32;

        // issue global loads early
        const f16* psrc = phb + (size_t)(kv0 + prow) * CI + pcol;
        const f16* gsrc = gTb + (size_t)growi * NN + kv0 + gcol;
        f16x8 pv0 = *reinterpret_cast<const f16x8*>(psrc);
        f16x8 pv1 = *reinterpret_cast<const f16x8*>(psrc + 8);
        f16x8 gv0 = *reinterpret_cast<const f16x8*>(gsrc);
        f16x8 gv1 = *reinterpret_cast<const f16x8*>(gsrc + 8);

        __syncthreads();
        *reinterpret_cast<f16x8*>(&ph_lds[prow*128 + (pcol ^ pswz)])       = pv0;
        *reinterpret_cast<f16x8*>(&ph_lds[prow*128 + ((pcol + 8) ^ pswz)]) = pv1;
        *reinterpret_cast<f16x8*>(&g_lds[growi*32 + gc0])                  = gv0;
        *reinterpret_cast<f16x8*>(&g_lds[growi*32 + gc1])                  = gv1;
        __syncthreads();

        // ---- S^T = phi @ theta^T : 2 kv-tiles x 2 q-tiles ----
        f32x4 s00 = (f32x4){0.f,0.f,0.f,0.f}, s01 = (f32x4){0.f,0.f,0.f,0.f};
        f32x4 s10 = (f32x4){0.f,0.f,0.f,0.f}, s11 = (f32x4){0.f,0.f,0.f,0.f};
        const int xsw = (l15 & 7) << 3;
        #pragma unroll
        for (int kk = 0; kk < 4; ++kk) {
            const int coff = (kk*32 + lg*8) ^ xsw;
            f16x8 a0 = *reinterpret_cast<const f16x8*>(&ph_lds[l15*128 + coff]);
            f16x8 a1 = *reinterpret_cast<const f16x8*>(&ph_lds[(16 + l15)*128 + coff]);
            s00 = __builtin_amdgcn_mfma_f32_16x16x32_f16(a0, bf[0][kk], s00, 0, 0, 0);
            s01 = __builtin_amdgcn_mfma_f32_16x16x32_f16(a1, bf[0][kk], s01, 0, 0, 0);
            s10 = __builtin_amdgcn_mfma_f32_16x16x32_f16(a0, bf[1][kk], s10, 0, 0, 0);
            s11 = __builtin_amdgcn_mfma_f32_16x16x32_f16(a1, bf[1][kk], s11, 0, 0, 0);
        }

        // ---- online max per q-tile (lane-local column), defer-rescale ----
        float tm0 = fmaxf(fmaxf(fmaxf(s00[0], s00[1]), fmaxf(s00[2], s00[3])),
                          fmaxf(fmaxf(s01[0], s01[1]), fmaxf(s01[2], s01[3])));
        float tm1 = fmaxf(fmaxf(fmaxf(s10[0], s10[1]), fmaxf(s10[2], s10[3])),
                          fmaxf(fmaxf(s11[0], s11[1]), fmaxf(s11[2], s11[3])));
        tm0 = fmaxf(tm0, __shfl_xor(tm0, 16));
        tm0 = fmaxf(tm0, __shfl_xor(tm0, 32));
        tm1 = fmaxf(tm1, __shfl_xor(tm1, 16));
        tm1 = fmaxf(tm1, __shfl_xor(tm1, 32));
        if (__any((tm0 > m[0] + THR) || (tm1 > m[1] + THR))) {
            float nm0 = fmaxf(m[0], tm0), nm1 = fmaxf(m[1], tm1);
            float sc0 = __builtin_amdgcn_exp2f(m[0] - nm0);
            float sc1 = __builtin_amdgcn_exp2f(m[1] - nm1);
            m[0] = nm0; m[1] = nm1;
            #pragma unroll
            for (int ct = 0; ct < 8; ++ct) {
                acc[0][ct][0] *= sc0; acc[0][ct][1] *= sc0; acc[0][ct][2] *= sc0; acc[0][ct][3] *= sc0;
                acc[1][ct][0] *= sc1; acc[1][ct][1] *= sc1; acc[1][ct][2] *= sc1; acc[1][ct][3] *= sc1;
            }
            accl[0][0] *= sc0; accl[0][1] *= sc0; accl[0][2] *= sc0; accl[0][3] *= sc0;
            accl[1][0] *= sc1; accl[1][1] *= sc1; accl[1][2] *= sc1; accl[1][3] *= sc1;
        }

        // ---- P^T = exp2(S^T - m), pack f16, exchange via per-wave LDS ----
        {
            union { fp16v2 h[2]; float2 f; } u0, u1;
            u0.h[0] = __builtin_amdgcn_cvt_pkrtz(__builtin_amdgcn_exp2f(s00[0] - m[0]),
                                                 __builtin_amdgcn_exp2f(s00[1] - m[0]));
            u0.h[1] = __builtin_amdgcn_cvt_pkrtz(__builtin_amdgcn_exp2f(s00[2] - m[0]),
                                                 __builtin_amdgcn_exp2f(s00[3] - m[0]));
            u1.h[0] = __builtin_amdgcn_cvt_pkrtz(__builtin_amdgcn_exp2f(s01[0] - m[0]),
                                                 __builtin_amdgcn_exp2f(s01[1] - m[0]));
            u1.h[1] = __builtin_amdgcn_cvt_pkrtz(__builtin_amdgcn_exp2f(s01[2] - m[0]),
                                                 __builtin_amdgcn_exp2f(s01[3] - m[0]));
            *reinterpret_cast<float2*>(&pT_lds[wid][0][l15][4*lg])      = u0.f;
            *reinterpret_cast<float2*>(&pT_lds[wid][0][l15][16 + 4*lg]) = u1.f;
            u0.h[0] = __builtin_amdgcn_cvt_pkrtz(__builtin_amdgcn_exp2f(s10[0] - m[1]),
                                                 __builtin_amdgcn_exp2f(s10[1] - m[1]));
            u0.h[1] = __builtin_amdgcn_cvt_pkrtz(__builtin_amdgcn_exp2f(s10[2] - m[1]),
                                                 __builtin_amdgcn_exp2f(s10[3] - m[1]));
            u1.h[0] = __builtin_amdgcn_cvt_pkrtz(__builtin_amdgcn_exp2f(s11[0] - m[1]),
                                                 __builtin_amdgcn_exp2f(s11[1] - m[1]));
            u1.h[1] = __builtin_amdgcn_cvt_pkrtz(__builtin_amdgcn_exp2f(s11[2] - m[1]),
                                                 __builtin_amdgcn_exp2f(s11[3] - m[1]));
            *reinterpret_cast<float2*>(&pT_lds[wid][1][l15][4*lg])      = u0.f;
            *reinterpret_cast<float2*>(&pT_lds[wid][1][l15][16 + 4*lg]) = u1.f;
        }
        asm volatile("s_waitcnt lgkmcnt(0)" ::: "memory");
        f16x8 pa0 = *reinterpret_cast<const f16x8*>(&pT_lds[wid][0][l15][8*lg]);
        f16x8 pa1 = *reinterpret_cast<const f16x8*>(&pT_lds[wid][1][l15][8*lg]);

        // ---- Y^T += gT @ P^T (swizzled g reads, conflict-free) ----
        const int grsw = ((l15 >> 1) & 3) << 3;
        #pragma unroll
        for (int ct = 0; ct < 8; ++ct) {
            f16x8 ga = *reinterpret_cast<const f16x8*>(&g_lds[(ct*16 + l15)*32 + (lg*8 ^ grsw)]);
            acc[0][ct] = __builtin_amdgcn_mfma_f32_16x16x32_f16(ga, pa0, acc[0][ct], 0, 0, 0);
            acc[1][ct] = __builtin_amdgcn_mfma_f32_16x16x32_f16(ga, pa1, acc[1][ct], 0, 0, 0);
        }
        accl[0] = __builtin_amdgcn_mfma_f32_16x16x32_f16(onesA, pa0, accl[0], 0, 0, 0);
        accl[1] = __builtin_amdgcn_mfma_f32_16x16x32_f16(onesA, pa1, accl[1], 0, 0, 0);
    }

    // ---- store partials: pacc[bs][ci][n] ----
    #pragma unroll
    for (int qt = 0; qt < 2; ++qt) {
        float* pb = pacc + (size_t)(b*SEG + seg) * CI * NN + qw + qt*16 + l15;
        #pragma unroll
        for (int ct = 0; ct < 8; ++ct)
            #pragma unroll
            for (int r = 0; r < 4; ++r)
                pb[(size_t)(ct*16 + lg*4 + r) * NN] = acc[qt][ct][r];
    }

    if (lg == 0) {
        #pragma unroll
        for (int qt = 0; qt < 2; ++qt) {
            float* mlb = pml + ((size_t)(b*SEG + seg) * NN + qw + qt*16 + l15) * 2;
            mlb[0] = m[qt];
            mlb[1] = accl[qt][0];
        }
    }
}

// ---------------- kernel 3: merge split-KV partials -> yh (f16 [pos][ci]) -----------
__global__ __launch_bounds__(256) void combine_kernel(
    const float* __restrict__ pacc, const float* __restrict__ pml,
    f16* __restrict__ yh)
{
    const int qL = threadIdx.x & 31;
    const int cg = threadIdx.x >> 5;          // 0..7, 16 ci each
    const int q  = blockIdx.x * 32 + qL;
    const int b  = blockIdx.y;

    float mv[SEG], lv[SEG];
    #pragma unroll
    for (int s = 0; s < SEG; ++s) {
        const float* p = pml + ((size_t)(b*SEG + s) * NN + q) * 2;
        mv[s] = p[0];
        lv[s] = p[1];
    }
    float M = mv[0];
    #pragma unroll
    for (int s = 1; s < SEG; ++s) M = fmaxf(M, mv[s]);
    float wsum = 0.f, w[SEG];
    #pragma unroll
    for (int s = 0; s < SEG; ++s) {
        w[s] = __builtin_amdgcn_exp2f(mv[s] - M);
        wsum = fmaf(w[s], lv[s], wsum);
    }
    const float inv = 1.0f / wsum;

    const int c0 = cg * 16;
    float o[16];
    #pragma unroll
    for (int i = 0; i < 16; ++i) o[i] = 0.f;
    for (int s = 0; s < SEG; ++s) {
        const float* pb = pacc + ((size_t)(b*SEG + s) * CI + c0) * NN + q;
        #pragma unroll
        for (int i = 0; i < 16; ++i)
            o[i] = fmaf(w[s], pb[(size_t)i * NN], o[i]);
    }
    f16 oh[16];
    #pragma unroll
    for (int i = 0; i < 16; ++i) oh[i] = (f16)(o[i] * inv);
    f16* yo = yh + ((size_t)b * NN + q) * CI + c0;
    *reinterpret_cast<f16x8*>(yo)     = *reinterpret_cast<f16x8*>(&oh[0]);
    *reinterpret_cast<f16x8*>(yo + 8) = *reinterpret_cast<f16x8*>(&oh[8]);
}

// ---------------- kernel 4: out GEMM (MFMA) + BN + residual ----------------
__global__ __launch_bounds__(256) void out_gemm(
    const float* __restrict__ x, const f16* __restrict__ yh, const f16* __restrict__ WoT,
    const float* __restrict__ bnsc, const float* __restrict__ bnsh, float* __restrict__ out)
{
    const int tid = threadIdx.x;
    const int wid = tid >> 6, lane = tid & 63;
    const int l15 = lane & 15, lg = lane >> 4;
    const int p0 = blockIdx.x * 16;
    const int nq = wid;

    f32x4 acc[4];
    #pragma unroll
    for (int t = 0; t < 4; ++t) acc[t] = (f32x4){0.f,0.f,0.f,0.f};

    const f16* ya = yh + (size_t)(p0 + l15)*CI + lg*8;
    const f16* wb = WoT + (size_t)(nq*64 + l15)*CI + lg*8;
    #pragma unroll
    for (int kk = 0; kk < 4; ++kk) {
        f16x8 a = *reinterpret_cast<const f16x8*>(ya + kk*32);
        #pragma unroll
        for (int t = 0; t < 4; ++t) {
            f16x8 bfr = *reinterpret_cast<const f16x8*>(wb + (size_t)t*16*CI + kk*32);
            acc[t] = __builtin_amdgcn_mfma_f32_16x16x32_f16(a, bfr, acc[t], 0, 0, 0);
        }
    }

    #pragma unroll
    for (int t = 0; t < 4; ++t) {
        const int ci = nq*64 + t*16 + l15;
        const float sc = bnsc[ci], sh = bnsh[ci];
        #pragma unroll
        for (int r = 0; r < 4; ++r) {
            const size_t idx = (size_t)(p0 + lg*4 + r)*CC + ci;
            out[idx] = x[idx] + fmaf(sc, acc[t][r], sh);
        }
    }
}

extern "C" void kernel_launch(void* const* d_in, const int* in_sizes, int n_in,
                              void* d_out, int out_size, void* d_ws, size_t ws_size,
                              hipStream_t stream)
{
    const float* x     = (const float*)d_in[0];
    const float* Wg    = (const float*)d_in[1];
    const float* bg    = (const float*)d_in[2];
    const float* Wt    = (const float*)d_in[3];
    const float* bt    = (const float*)d_in[4];
    const float* Wp    = (const float*)d_in[5];
    const float* bp    = (const float*)d_in[6];
    const float* Wo    = (const float*)d_in[7];
    const float* bo    = (const float*)d_in[8];
    const float* gamma = (const float*)d_in[9];
    const float* beta  = (const float*)d_in[10];
    const float* mmean = (const float*)d_in[11];
    const float* mvar  = (const float*)d_in[12];
    float* out = (float*)d_out;

    const size_t PB = (size_t)BB * NN * CI;                 // 1,605,632
    f16*   th   = (f16*)d_ws;                               // 3.2 MB
    f16*   ph   = th + PB;                                  // 3.2 MB
    f16*   gT   = ph + PB;                                  // 3.2 MB
    float* pacc = (float*)(gT + PB);                        // 45 MB [bs][ci][n]
    float* pml  = pacc + (size_t)BB * SEG * NN * CI;        // 0.7 MB
    f16*   yh   = (f16*)(pml + (size_t)BB * SEG * NN * 2);  // 3.2 MB
    f16*   WallT= yh + PB;                                  // 197 KB
    f16*   WoT  = WallT + 384*256;                          // 66 KB
    float* ball = (float*)(WoT + 256*CI);                   // 1.5 KB
    float* bnsc = ball + 384;
    float* bnsh = bnsc + 256;

    prep_kernel<<<516, 256, 0, stream>>>(Wg, Wt, Wp, Wo, bg, bt, bp, bo,
                                         gamma, beta, mmean, mvar,
                                         WallT, WoT, ball, bnsc, bnsh);
    proj_gemm<<<BB * NN / 16, 256, 0, stream>>>(x, WallT, ball, th, ph, gT);
    attn_kernel<<<dim3(NN / 128, SEG, BB), 256, 0, stream>>>(th, ph, gT, pacc, pml);
    combine_kernel<<<dim3(NN / 32, BB), 256, 0, stream>>>(pacc, pml, yh);
    out_gemm<<<BB * NN / 16, 256, 0, stream>>>(x, yh, WoT, bnsc, bnsh, out);
}